// Round 1
// 126.306 us; speedup vs baseline: 1.0805x; 1.0805x over previous
//
#include <hip/hip_runtime.h>
#include <math.h>

// Problem constants
// B=4096, SEQ=C=8, L=2048, NK=256, NCLS=100, EBIT=16, EBDIN=4, D=4
// nk enumeration: [0,768) = w3 (n*3+k), [768,1792) = w4, [1792,3072) = w5
// feature rows: K=3 -> n*6+p, K=4 -> 1536+n*5+p, K=5 -> 2816+n*4+p
//
// R layout is TRANSPOSED vs earlier sessions: R[nk*128 + (h*16+j)].
//  - k_Rz writes become 2 coalesced 256B stores per wave (was 2x 64-line scatters)
//  - k_G reads become 4 uniform contiguous float4 (1 cacheline) per tap (was 16
//    loads striding 12KB -> 16 cachelines)

// Kernel 1: one wave per nk. Butterfly-reduce the 5 dots (w_nk . We_d, w_nk . be),
// then expand over the 128 (h,j) LUT combos into R[nk*128 + rr].
// Block 0 additionally zero-inits G (ws is poisoned 0xAA each launch).
__global__ void k_Rz(const float* __restrict__ We, const float* __restrict__ be,
                     const float* __restrict__ w3, const float* __restrict__ w4,
                     const float* __restrict__ w5, const float* __restrict__ LUT,
                     float* __restrict__ R, float* __restrict__ G) {
  int tid = threadIdx.x;            // 256 = 4 waves
  if (blockIdx.x == 0) {
    for (int i = tid; i < 12800; i += 256) G[i] = 0.f;
  }
  int lane = tid & 63;
  int nk = blockIdx.x * 4 + (tid >> 6);   // 0..3071
  const float* wrow;
  if (nk < 768)       wrow = w3 + nk * 2048;
  else if (nk < 1792) wrow = w4 + (nk - 768) * 2048;
  else                wrow = w5 + (nk - 1792) * 2048;
  float a0 = 0.f, a1 = 0.f, a2 = 0.f, a3 = 0.f, a4 = 0.f;
  const float4* wp  = (const float4*)wrow;
  const float4* e0p = (const float4*)(We);
  const float4* e1p = (const float4*)(We + 2048);
  const float4* e2p = (const float4*)(We + 4096);
  const float4* e3p = (const float4*)(We + 6144);
  const float4* bep = (const float4*)(be);
#pragma unroll
  for (int i = lane; i < 512; i += 64) {
    float4 w = wp[i];
    float4 e0 = e0p[i], e1 = e1p[i], e2 = e2p[i], e3 = e3p[i], bb = bep[i];
    a0 += w.x * e0.x + w.y * e0.y + w.z * e0.z + w.w * e0.w;
    a1 += w.x * e1.x + w.y * e1.y + w.z * e1.z + w.w * e1.w;
    a2 += w.x * e2.x + w.y * e2.y + w.z * e2.z + w.w * e2.w;
    a3 += w.x * e3.x + w.y * e3.y + w.z * e3.z + w.w * e3.w;
    a4 += w.x * bb.x + w.y * bb.y + w.z * bb.z + w.w * bb.w;
  }
#pragma unroll
  for (int off = 32; off > 0; off >>= 1) {
    a0 += __shfl_xor(a0, off, 64);
    a1 += __shfl_xor(a1, off, 64);
    a2 += __shfl_xor(a2, off, 64);
    a3 += __shfl_xor(a3, off, 64);
    a4 += __shfl_xor(a4, off, 64);
  }
  // all lanes now hold the full sums; lanes cover the 128 (h,j) combos, 2 each
#pragma unroll
  for (int r = 0; r < 2; r++) {
    int rr = lane + r * 64;       // h*16+j
    const float* lut = LUT + rr * 4;
    float v = a4 + lut[0] * a0 + lut[1] * a1 + lut[2] * a2 + lut[3] * a3;
    R[nk * 128 + rr] = fmaxf(v, 0.f);   // coalesced: lanes write consecutive floats
  }
}

// Kernel 2: G[h,j,c] += sum over this block's 32-nk chunk of R[nk][h*16+j]*W2[row(h,nk),c]
// grid = (8 h, 96 chunks of 32 nk), block = 128 threads (c).
// R reads are block-uniform contiguous float4 (single cacheline per tap).
__global__ void k_G(const float* __restrict__ R, const float* __restrict__ W2,
                    float* __restrict__ G) {
  int h = blockIdx.x;
  int z = blockIdx.y;
  int c = threadIdx.x;
  int nk0 = z * 32;
  int K, P, rowbase, n0, k0;
  if (nk0 < 768)       { K = 3; P = 6; rowbase = 0;    n0 = nk0 / 3;  k0 = nk0 - n0 * 3; }
  else if (nk0 < 1792) { K = 4; P = 5; rowbase = 1536; int t2 = nk0 - 768;  n0 = t2 >> 2; k0 = t2 & 3; }
  else                 { K = 5; P = 4; rowbase = 2816; int t2 = nk0 - 1792; n0 = t2 / 5;  k0 = t2 - n0 * 5; }
  float acc[16];
#pragma unroll
  for (int j = 0; j < 16; j++) acc[j] = 0.f;
  bool act = c < 100;
  int n = n0, k = k0;
#pragma unroll
  for (int it = 0; it < 32; ++it) {
    int nk = nk0 + it;
    int p = h - k;
    if (p >= 0 && p < P) {
      float w2v = act ? W2[(rowbase + n * P + p) * 100 + c] : 0.f;
      const float4* Rp = (const float4*)(R + nk * 128 + h * 16);  // block-uniform
      float4 r0 = Rp[0], r1 = Rp[1], r2 = Rp[2], r3 = Rp[3];
      acc[0]  += r0.x * w2v; acc[1]  += r0.y * w2v; acc[2]  += r0.z * w2v; acc[3]  += r0.w * w2v;
      acc[4]  += r1.x * w2v; acc[5]  += r1.y * w2v; acc[6]  += r1.z * w2v; acc[7]  += r1.w * w2v;
      acc[8]  += r2.x * w2v; acc[9]  += r2.y * w2v; acc[10] += r2.z * w2v; acc[11] += r2.w * w2v;
      acc[12] += r3.x * w2v; acc[13] += r3.y * w2v; acc[14] += r3.z * w2v; acc[15] += r3.w * w2v;
    }
    if (++k == K) { k = 0; ++n; }
  }
  if (act) {
#pragma unroll
    for (int j = 0; j < 16; j++) atomicAdd(&G[(h * 16 + j) * 100 + c], acc[j]);
  }
}

// Kernel 3: 256 threads = 4 waves, one wave per b (grid 1024).
// Phase 1 now uses ALL 64 lanes: 8 lanes per position. Each lane accumulates
// 2 of the 16 embedding terms of hv (3-level shfl reduce), computes sg
// redundantly within its 8-lane group, evaluates 2 of the 16 j-candidates,
// then a tie-aware cross-lane argmax reproduces serial first-max semantics.
__global__ void k_out(const int* __restrict__ x, const float* __restrict__ len_emb,
                      const float* __restrict__ ipd_emb, const float* __restrict__ W1,
                      const float* __restrict__ b1, const float* __restrict__ S,
                      const float* __restrict__ Hm, const float* __restrict__ T,
                      const float* __restrict__ G, const float* __restrict__ b2,
                      float* __restrict__ out) {
  int b = blockIdx.x * 4 + (threadIdx.x >> 6);
  int t = threadIdx.x & 63;  // lane within wave
  int pos = t >> 3;          // 0..7 : sequence position
  int s   = t & 7;           // 0..7 : worker within position group
  int bh = b * 8 + pos;
  // detect int64 vs int32 x: if int64 (values < 256), all high words are 0
  bool is64 = true;
#pragma unroll
  for (int q = 0; q < 16; q++) is64 = is64 && (x[2 * q + 1] == 0);
  int i0, i1;
  if (is64) { i0 = x[4 * bh]; i1 = x[4 * bh + 2]; }
  else      { i0 = x[2 * bh]; i1 = x[2 * bh + 1]; }
  const float* le = len_emb + i0 * 16;
  const float* ie = ipd_emb + i1 * 16;
  // distributed hv: lane s covers embedding dims {s, s+8}
  float hv[4] = {0.f, 0.f, 0.f, 0.f};
#pragma unroll
  for (int u = 0; u < 2; u++) {
    int i = s + u * 8;
    float lv = le[i], iv = ie[i];
#pragma unroll
    for (int d = 0; d < 4; d++) hv[d] += lv * W1[i * 4 + d] + iv * W1[(16 + i) * 4 + d];
  }
#pragma unroll
  for (int off = 1; off < 8; off <<= 1) {
#pragma unroll
    for (int d = 0; d < 4; d++) hv[d] += __shfl_xor(hv[d], off, 64);
  }
#pragma unroll
  for (int d = 0; d < 4; d++) hv[d] += b1[d];
  // sg computed redundantly by all 8 lanes of the group
  float sg[15];
#pragma unroll
  for (int kk = 0; kk < 15; kk++) {
    float m = -1e-4f - T[pos * 15 + kk];
#pragma unroll
    for (int d = 0; d < 4; d++) m += hv[d] * S[(pos * 4 + d) * 15 + kk];
    sg[kk] = (m > 0.f) ? 1.f : ((m < 0.f) ? -1.f : 0.f);
  }
  // lane s evaluates j = 2s and 2s+1 (ascending-kk order matches old serial code)
  float bv = -INFINITY; int bj = 0;
#pragma unroll
  for (int jj = 0; jj < 2; jj++) {
    int j = 2 * s + jj;
    float v = 0.f;
#pragma unroll
    for (int kk = 0; kk < 15; kk++) v += sg[kk] * Hm[kk * 16 + j];
    if (v > bv) { bv = v; bj = j; }   // strict > keeps first max within lane
  }
  // cross-lane argmax within the 8-lane group; on exact tie prefer smaller j
#pragma unroll
  for (int off = 1; off < 8; off <<= 1) {
    float ov = __shfl_xor(bv, off, 64);
    int   oj = __shfl_xor(bj, off, 64);
    if (ov > bv || (ov == bv && oj < bj)) { bv = ov; bj = oj; }
  }
  // lane p*8 holds position p's argmax
  int js[8];
#pragma unroll
  for (int p = 0; p < 8; p++) js[p] = __shfl(bj, p * 8, 64);
  int c0 = t, c1 = t + 64;
  float v0, v1 = -INFINITY;
  {
    float a = b2[c0];
#pragma unroll
    for (int p = 0; p < 8; p++) a += G[(p * 16 + js[p]) * 100 + c0];
    v0 = a;
  }
  if (c1 < 100) {
    float a = b2[c1];
#pragma unroll
    for (int p = 0; p < 8; p++) a += G[(p * 16 + js[p]) * 100 + c1];
    v1 = a;
  }
  float mx = fmaxf(v0, v1);
#pragma unroll
  for (int off = 32; off > 0; off >>= 1) mx = fmaxf(mx, __shfl_xor(mx, off, 64));
  float e = expf(v0 - mx) + ((c1 < 100) ? expf(v1 - mx) : 0.f);
#pragma unroll
  for (int off = 32; off > 0; off >>= 1) e += __shfl_xor(e, off, 64);
  float lse = mx + logf(e);
  out[b * 100 + c0] = v0 - lse;
  if (c1 < 100) out[b * 100 + c1] = v1 - lse;
}

extern "C" void kernel_launch(void* const* d_in, const int* in_sizes, int n_in,
                              void* d_out, int out_size, void* d_ws, size_t ws_size,
                              hipStream_t stream) {
  const int*   x       = (const int*)  d_in[0];
  const float* len_emb = (const float*)d_in[1];
  const float* ipd_emb = (const float*)d_in[2];
  const float* W1      = (const float*)d_in[3];
  const float* b1      = (const float*)d_in[4];
  const float* We      = (const float*)d_in[5];
  const float* be      = (const float*)d_in[6];
  const float* w3      = (const float*)d_in[7];
  const float* w4      = (const float*)d_in[8];
  const float* w5      = (const float*)d_in[9];
  const float* W2      = (const float*)d_in[10];
  const float* b2      = (const float*)d_in[11];
  const float* S       = (const float*)d_in[12];
  const float* Hm      = (const float*)d_in[13];
  const float* T       = (const float*)d_in[14];
  const float* LUT     = (const float*)d_in[15];
  float* out = (float*)d_out;

  // R (3072*128 f32 = 1.5 MB, transposed layout) lives in d_out (dead before
  // k_out overwrites it). G (12800 f32) lives at the start of ws.
  float* R = (float*)d_out;
  float* G = (float*)d_ws;

  k_Rz<<<768, 256, 0, stream>>>(We, be, w3, w4, w5, LUT, R, G);
  dim3 gB(8, 96);
  k_G<<<gB, 128, 0, stream>>>(R, W2, G);
  k_out<<<1024, 256, 0, stream>>>(x, len_emb, ipd_emb, W1, b1, S, Hm, T, G, b2, out);
}